// Round 10
// baseline (183.663 us; speedup 1.0000x reference)
//
#include <hip/hip_runtime.h>
#include <hip/hip_bf16.h>

#define D 45
#define LSEQ 4096
#define NB 8
#define U 45
#define FH 128
#define KPAD 48        // padded row length (elems) for bf16 hi/lo buffers
#define TOPC 64        // screened candidate count (rescreened exactly)
#define SSPLIT 8       // s-range slices for qkmax
#define CH 64          // attn_pv rows per chunk
#define NCH (LSEQ / CH)  // 64 chunks
constexpr float LN_EPS = 1e-12f;

typedef __attribute__((ext_vector_type(8))) short short8v;    // 8 x bf16
typedef __attribute__((ext_vector_type(4))) float float4v;    // 16x16 MFMA C/D
typedef __attribute__((ext_vector_type(16))) float float16v;  // 32x32 MFMA C/D

// ---------------------------------------------------------------------------
// Kernel 1: split-bf16 conversion.
//   z=0: Xh/Xl[b][l][0..47]  = hi/lo(x[b][l][d])  (row-major, zero-padded)
//   z=1: Kh/Kl[b][s][0..47]  = hi/lo(x[b][idx[s]][d]) + per-chunk Ksum partials
// ---------------------------------------------------------------------------
__global__ __launch_bounds__(256) void convert_kernel(const float* __restrict__ x,
                                                      const int* __restrict__ idx,
                                                      ushort* __restrict__ Xh, ushort* __restrict__ Xl,
                                                      ushort* __restrict__ Kh, ushort* __restrict__ Kl,
                                                      float* __restrict__ Ksump) {
  const int c = blockIdx.x, b = blockIdx.y, z = blockIdx.z;
  const int tid = threadIdx.x;
  const int r0 = c * 256;
  const float* xb = x + (size_t)b * LSEQ * D;
  ushort* dh = (z == 0 ? Xh : Kh) + ((size_t)b * LSEQ + r0) * KPAD;
  ushort* dl = (z == 0 ? Xl : Kl) + ((size_t)b * LSEQ + r0) * KPAD;
  for (int i = tid; i < 256 * KPAD; i += 256) {
    const int j = i / KPAD, d = i - j * KPAD;
    const int row = (z == 0) ? (r0 + j) : idx[r0 + j];
    const float v = (d < D) ? xb[(size_t)row * D + d] : 0.0f;
    __hip_bfloat16 h = __float2bfloat16(v);
    const float hf = __bfloat162float(h);
    __hip_bfloat16 lo = __float2bfloat16(v - hf);
    dh[i] = reinterpret_cast<ushort&>(h);
    dl[i] = reinterpret_cast<ushort&>(lo);
  }
  if (z == 1) {  // deterministic per-chunk Ksum partial (combined later)
    __shared__ float kp[4][KPAD];
    const int g = tid >> 6, d = tid & 63;
    float acc = 0.f;
    if (d < D)
      for (int j = g; j < 256; j += 4) acc += xb[(size_t)idx[r0 + j] * D + d];
    if (d < KPAD) kp[g][d] = (d < D) ? acc : 0.f;
    __syncthreads();
    if (tid < D)
      Ksump[((size_t)b * 16 + c) * KPAD + tid] =
          kp[0][tid] + kp[1][tid] + kp[2][tid] + kp[3][tid];
  }
}

// ---------------------------------------------------------------------------
// Kernel 2 (HOT): split-bf16 MFMA QK^T row-max via 32x32x16 (K padded to 48,
// 3 k-steps — 94% useful FLOP vs 70% for the 16x16x32 K=64 pad).
// Wave owns 2 l-tiles (64 rows); 9 MFMA per tile per 32-key step
// (hh,hl,lh x 3 ksteps). A layout: row=lane&31, k=(lane>>5)*8+j.
// C/D layout (m74/m101): col=lane&31, row=(reg&3)+8*(reg>>2)+4*(lane>>5).
// ---------------------------------------------------------------------------
__global__ __launch_bounds__(256) void qkmax_kernel(const ushort* __restrict__ Xh,
                                                    const ushort* __restrict__ Xl,
                                                    const ushort* __restrict__ Kh,
                                                    const ushort* __restrict__ Kl,
                                                    float* __restrict__ Mpart) {
  const int b = blockIdx.y, sc = blockIdx.z;
  const int tid = threadIdx.x, lane = tid & 63, wv = tid >> 6;
  const int l0 = blockIdx.x * 256 + wv * 64;  // wave's 64 q-rows (2 tiles of 32)
  const int r32 = lane & 31, hh = lane >> 5;
  const int kbase = hh * 8;

  // A fragments: 2 tiles x 3 ksteps, hi and lo
  short8v AH[2][3], AL[2][3];
#pragma unroll
  for (int t = 0; t < 2; ++t) {
    const ushort* xh = Xh + ((size_t)b * LSEQ + l0 + t * 32 + r32) * KPAD + kbase;
    const ushort* xl = Xl + ((size_t)b * LSEQ + l0 + t * 32 + r32) * KPAD + kbase;
#pragma unroll
    for (int ks = 0; ks < 3; ++ks) {
      AH[t][ks] = *(const short8v*)(xh + ks * 16);
      AL[t][ks] = *(const short8v*)(xl + ks * 16);
    }
  }

  const ushort* khB = Kh + ((size_t)b * LSEQ + sc * (LSEQ / SSPLIT) + r32) * KPAD + kbase;
  const ushort* klB = Kl + ((size_t)b * LSEQ + sc * (LSEQ / SSPLIT) + r32) * KPAD + kbase;

  float16v mx[2];
#pragma unroll
  for (int t = 0; t < 2; ++t)
#pragma unroll
    for (int r = 0; r < 16; ++r) mx[t][r] = -INFINITY;

  for (int st = 0; st < (LSEQ / SSPLIT) / 32; ++st) {
    const ushort* kh = khB + (size_t)st * 32 * KPAD;
    const ushort* kl = klB + (size_t)st * 32 * KPAD;
    short8v BH[3], BL[3];
#pragma unroll
    for (int ks = 0; ks < 3; ++ks) {
      BH[ks] = *(const short8v*)(kh + ks * 16);
      BL[ks] = *(const short8v*)(kl + ks * 16);
    }
    float16v a0 = {0.f, 0.f, 0.f, 0.f, 0.f, 0.f, 0.f, 0.f,
                   0.f, 0.f, 0.f, 0.f, 0.f, 0.f, 0.f, 0.f};
    float16v a1 = a0;
#pragma unroll
    for (int ks = 0; ks < 3; ++ks) {
      a0 = __builtin_amdgcn_mfma_f32_32x32x16_bf16(AH[0][ks], BH[ks], a0, 0, 0, 0);
      a1 = __builtin_amdgcn_mfma_f32_32x32x16_bf16(AH[1][ks], BH[ks], a1, 0, 0, 0);
    }
#pragma unroll
    for (int ks = 0; ks < 3; ++ks) {
      a0 = __builtin_amdgcn_mfma_f32_32x32x16_bf16(AH[0][ks], BL[ks], a0, 0, 0, 0);
      a1 = __builtin_amdgcn_mfma_f32_32x32x16_bf16(AH[1][ks], BL[ks], a1, 0, 0, 0);
    }
#pragma unroll
    for (int ks = 0; ks < 3; ++ks) {
      a0 = __builtin_amdgcn_mfma_f32_32x32x16_bf16(AL[0][ks], BH[ks], a0, 0, 0, 0);
      a1 = __builtin_amdgcn_mfma_f32_32x32x16_bf16(AL[1][ks], BH[ks], a1, 0, 0, 0);
    }
#pragma unroll
    for (int r = 0; r < 16; ++r) {
      mx[0][r] = fmaxf(mx[0][r], a0[r]);
      mx[1][r] = fmaxf(mx[1][r], a1[r]);
    }
  }

  // reduce over the 32 key-columns (lane&31) within each half; store per row
#pragma unroll
  for (int t = 0; t < 2; ++t)
#pragma unroll
    for (int r = 0; r < 16; ++r) {
      float v = mx[t][r];
      v = fmaxf(v, __shfl_xor(v, 1));
      v = fmaxf(v, __shfl_xor(v, 2));
      v = fmaxf(v, __shfl_xor(v, 4));
      v = fmaxf(v, __shfl_xor(v, 8));
      v = fmaxf(v, __shfl_xor(v, 16));
      if (r32 == 0) {
        const int row = (r & 3) + 8 * (r >> 2) + 4 * hh;
        Mpart[((size_t)sc * NB + b) * LSEQ + l0 + t * 32 + row] = v;
      }
    }
}

// ---------------------------------------------------------------------------
// Kernel 3: Mapx[b][l] = max_sc(Mpart) - dot(x_l, Ksum)/L   (fp32 mean term)
// ---------------------------------------------------------------------------
__global__ __launch_bounds__(256) void meanM_kernel(const float* __restrict__ x,
                                                    const float* __restrict__ Ksump,
                                                    const float* __restrict__ Mpart,
                                                    float* __restrict__ Mapx) {
  __shared__ float ks[KPAD];
  const int c = blockIdx.x, b = blockIdx.y;
  const int tid = threadIdx.x;
  if (tid < KPAD) {
    float s = 0.f;
    if (tid < D)
      for (int cc = 0; cc < 16; ++cc) s += Ksump[((size_t)b * 16 + cc) * KPAD + tid];
    ks[tid] = s;
  }
  __syncthreads();
  const int l = c * 256 + tid;
  const float* xr = x + ((size_t)b * LSEQ + l) * D;
  float dot = 0.f;
  for (int d = 0; d < D; ++d) dot = fmaf(xr[d], ks[d], dot);
  float mx = Mpart[(size_t)b * LSEQ + l];
  for (int sl = 1; sl < SSPLIT; ++sl)
    mx = fmaxf(mx, Mpart[((size_t)sl * NB + b) * LSEQ + l]);
  Mapx[(size_t)b * LSEQ + l] = mx - dot * (1.0f / LSEQ);
}

// ---------------------------------------------------------------------------
// Kernel 4: radix-select the top-64 candidate SET by approximate M.
// ---------------------------------------------------------------------------
__global__ __launch_bounds__(256) void topk_kernel(const float* __restrict__ Mapx,
                                                   int* __restrict__ Cand) {
  __shared__ int hist[256];
  __shared__ int wsum[4];
  __shared__ int bin_s, need_s, cntG_s, cntEq_s, minv_s;
  __shared__ int eqIdx[LSEQ];
  const int b = blockIdx.x;
  const int tid = threadIdx.x;
  const int lane = tid & 63, wv = tid >> 6;
  uint32_t kreg[16];
#pragma unroll
  for (int k2 = 0; k2 < 16; ++k2) {
    const int l = tid + (k2 << 8);
    uint32_t u = __float_as_uint(Mapx[(size_t)b * LSEQ + l]);
    u ^= (u & 0x80000000u) ? 0xFFFFFFFFu : 0x80000000u;
    kreg[k2] = u;
  }
  const uint32_t pmaskA[4] = {0u, 0xFF000000u, 0xFFFF0000u, 0xFFFFFF00u};
  uint32_t P = 0;
  int need = TOPC;
#pragma unroll
  for (int r = 0; r < 4; ++r) {
    const int shift = 24 - 8 * r;
    hist[tid] = 0;
    __syncthreads();
#pragma unroll
    for (int k2 = 0; k2 < 16; ++k2) {
      const uint32_t key = kreg[k2];
      if (((key ^ P) & pmaskA[r]) == 0) atomicAdd(&hist[(key >> shift) & 0xFF], 1);
    }
    __syncthreads();
    const int h = hist[255 - tid];
    int s = h;
#pragma unroll
    for (int off = 1; off < 64; off <<= 1) {
      int t2 = __shfl_up(s, off);
      if (lane >= off) s += t2;
    }
    if (lane == 63) wsum[wv] = s;
    __syncthreads();
    for (int w2 = 0; w2 < wv; ++w2) s += wsum[w2];
    const int above = s - h;
    if (above < need && s >= need) { bin_s = 255 - tid; need_s = need - above; }
    __syncthreads();
    P |= ((uint32_t)bin_s) << shift;
    need = need_s;
    __syncthreads();
  }
  const uint32_t T = P;

  if (tid == 0) { cntG_s = 0; cntEq_s = 0; }
  __syncthreads();
#pragma unroll
  for (int k2 = 0; k2 < 16; ++k2) {
    const uint32_t key = kreg[k2];
    const int l = tid + (k2 << 8);
    if (key > T) {
      Cand[b * TOPC + atomicAdd(&cntG_s, 1)] = l;
    } else if (key == T) {
      eqIdx[atomicAdd(&cntEq_s, 1)] = l;
    }
  }
  __syncthreads();
  const int G = cntG_s;
  const int nEq = cntEq_s;
  for (int j = 0; j < need; ++j) {
    int mv2 = 0x7FFFFFFF;
    for (int i = tid; i < nEq; i += 256) mv2 = min(mv2, eqIdx[i]);
#pragma unroll
    for (int off = 32; off; off >>= 1) mv2 = min(mv2, __shfl_xor(mv2, off));
    if (lane == 0) wsum[wv] = mv2;
    __syncthreads();
    if (tid == 0) {
      int m2 = min(min(wsum[0], wsum[1]), min(wsum[2], wsum[3]));
      Cand[b * TOPC + G + j] = m2;
      minv_s = m2;
    }
    __syncthreads();
    for (int i = tid; i < nEq; i += 256)
      if (eqIdx[i] == minv_s) eqIdx[i] = 0x7FFFFFFF;
    __syncthreads();
  }
}

// ---------------------------------------------------------------------------
// Kernel 5: exact fp32 rescreen — per 256-key chunk, Mcp[b][c][u] =
// max_s dot(q_cand_u, k_s). K chunk staged in LDS (broadcast reads).
// ---------------------------------------------------------------------------
__global__ __launch_bounds__(256) void rescreen_kernel(const float* __restrict__ x,
                                                       const int* __restrict__ idx,
                                                       const int* __restrict__ Cand,
                                                       float* __restrict__ Mcp) {
  __shared__ float Kr[256][KPAD];
  __shared__ float mred[4][TOPC];
  __shared__ int cl[TOPC];
  const int c = blockIdx.x, b = blockIdx.y;
  const int tid = threadIdx.x;
  const float* xb = x + (size_t)b * LSEQ * D;
  if (tid < TOPC) cl[tid] = Cand[b * TOPC + tid];
  for (int i = tid; i < 256 * D; i += 256) {
    const int j = i / D, d = i - j * D;
    Kr[j][d] = xb[(size_t)idx[c * 256 + j] * D + d];
  }
  __syncthreads();
  const int u = tid & 63, sub = tid >> 6;
  const float* qr = xb + (size_t)cl[u] * D;
  float q[D];
#pragma unroll
  for (int d = 0; d < D; ++d) q[d] = qr[d];
  float mm = -INFINITY;
  for (int s = sub * 64; s < sub * 64 + 64; ++s) {
    float a0 = 0.f, a1 = 0.f;
#pragma unroll
    for (int d = 0; d < 44; d += 4) {
      a0 = fmaf(q[d + 0], Kr[s][d + 0], a0);
      a1 = fmaf(q[d + 1], Kr[s][d + 1], a1);
      a0 = fmaf(q[d + 2], Kr[s][d + 2], a0);
      a1 = fmaf(q[d + 3], Kr[s][d + 3], a1);
    }
    a0 = fmaf(q[44], Kr[s][44], a0);
    mm = fmaxf(mm, a0 + a1);
  }
  mred[sub][u] = mm;
  __syncthreads();
  if (tid < TOPC)
    Mcp[((size_t)b * 16 + c) * TOPC + tid] =
        fmaxf(fmaxf(mred[0][tid], mred[1][tid]), fmaxf(mred[2][tid], mred[3][tid]));
}

// ---------------------------------------------------------------------------
// Kernel 6: exact top-45 among the 64 candidates (value desc, index asc —
// jax.lax.top_k tie order) and gather Qg.
// ---------------------------------------------------------------------------
__global__ __launch_bounds__(256) void select_kernel(const float* __restrict__ x,
                                                     const float* __restrict__ Ksump,
                                                     const int* __restrict__ Cand,
                                                     const float* __restrict__ Mcp,
                                                     float* __restrict__ Qg) {
  __shared__ float ks[KPAD];
  __shared__ unsigned long long keys[TOPC];
  __shared__ int sel[U];
  const int b = blockIdx.x;
  const int tid = threadIdx.x;
  if (tid < KPAD) {
    float s = 0.f;
    if (tid < D)
      for (int cc = 0; cc < 16; ++cc) s += Ksump[((size_t)b * 16 + cc) * KPAD + tid];
    ks[tid] = s;
  }
  __syncthreads();
  if (tid < TOPC) {
    const int l = Cand[b * TOPC + tid];
    float mx = -INFINITY;
    for (int c = 0; c < 16; ++c) mx = fmaxf(mx, Mcp[((size_t)b * 16 + c) * TOPC + tid]);
    const float* xr = x + ((size_t)b * LSEQ + l) * D;
    float dot = 0.f;
    for (int d = 0; d < D; ++d) dot = fmaf(xr[d], ks[d], dot);
    const float Mv = mx - dot * (1.0f / LSEQ);
    uint32_t u = __float_as_uint(Mv);
    u ^= (u & 0x80000000u) ? 0xFFFFFFFFu : 0x80000000u;
    keys[tid] = ((unsigned long long)u << 32) | (unsigned long long)(4095 - l);
  }
  __syncthreads();
  if (tid < TOPC) {
    const unsigned long long ku = keys[tid];
    int rank = 0;
    for (int v = 0; v < TOPC; ++v) rank += (keys[v] > ku);
    if (rank < U) sel[rank] = 4095 - (int)(ku & 0xFFFFFFFFull);
  }
  __syncthreads();
  const float* xb = x + (size_t)b * LSEQ * D;
  for (int i = tid; i < U * D; i += 256) {
    const int u2 = i / D, d = i - u2 * D;
    Qg[(size_t)b * U * D + i] = xb[(size_t)sel[u2] * D + d];
  }
}

// ---------------------------------------------------------------------------
// Kernel 7: sparse attention, 64-row chunks for occupancy.
// ---------------------------------------------------------------------------
__global__ __launch_bounds__(256) void attn_pv_kernel(const float* __restrict__ x,
                                                      const float* __restrict__ Qg,
                                                      float* __restrict__ PVpart) {
  __shared__ float Xs[CH][D + 2];  // [64][47], col 45 = 1.0
  __shared__ float eS[CH][D + 2];
  __shared__ float Qs[U * D];      // 8100 B
  const int chunk = blockIdx.x, b = blockIdx.y;
  const int tid = threadIdx.x;
  const int l0 = chunk * CH;
  const float* xb = x + ((size_t)b * LSEQ + l0) * D;
  for (int i = tid; i < CH * D; i += 256) {
    const int l = i / D, d = i - l * D;
    Xs[l][d] = xb[i];
  }
  const float* qb = Qg + (size_t)b * U * D;
  for (int i = tid; i < U * D; i += 256) Qs[i] = qb[i];
  if (tid < CH) Xs[tid][D] = 1.0f;
  __syncthreads();

  const int l = tid & 63, sub = tid >> 6;
  float xr[D];
#pragma unroll
  for (int d = 0; d < D; ++d) xr[d] = Xs[l][d];
  const float scale = 0.14907119849998599f;  // 1/sqrt(45)
  const int u0 = sub * 12;
  const int uend = (u0 + 12 < U) ? u0 + 12 : U;
  for (int u = u0; u < uend; ++u) {
    float acc = 0.f;
#pragma unroll
    for (int d = 0; d < D; ++d) acc = fmaf(Qs[u * D + d], xr[d], acc);  // uniform LDS bcast
    eS[l][u] = __expf(acc * scale);
  }
  __syncthreads();

  float* outp = PVpart + (size_t)(b * NCH + chunk) * (U * (D + 1));
  for (int idx2 = tid; idx2 < U * (D + 1); idx2 += 256) {
    const int u = idx2 / (D + 1), c = idx2 - u * (D + 1);
    float acc = 0.f;
#pragma unroll 4
    for (int ll = 0; ll < CH; ++ll) acc = fmaf(eS[ll][u], Xs[ll][c], acc);
    outp[idx2] = acc;
  }
}

// ---------------------------------------------------------------------------
// Kernel 8: parallel combine of NCH PV partials -> hC[b][u][0..45]
// ---------------------------------------------------------------------------
__global__ __launch_bounds__(256) void combine_kernel(const float* __restrict__ PVpart,
                                                      float* __restrict__ hC) {
  __shared__ float part[4][D + 1];
  const int u = blockIdx.x, b = blockIdx.y;
  const int tid = threadIdx.x;
  const int g = tid >> 6, col = tid & 63;
  if (col <= D) {
    const float* base = PVpart + ((size_t)b * NCH + g * (NCH / 4)) * (U * (D + 1)) +
                        (size_t)u * (D + 1) + col;
    float s = 0.f;
#pragma unroll 4
    for (int c = 0; c < NCH / 4; ++c) s += base[(size_t)c * (U * (D + 1))];
    part[g][col] = s;
  }
  __syncthreads();
  if (tid <= D)
    hC[((size_t)b * U + u) * (D + 1) + tid] =
        (part[0][tid] + part[1][tid]) + (part[2][tid] + part[3][tid]);
}

// ---------------------------------------------------------------------------
// Kernel 9: normalize -> LN1 -> FFN -> LN2 -> out. Reads only compact hC.
// ---------------------------------------------------------------------------
__global__ __launch_bounds__(256) void ffn_kernel(const float* __restrict__ hC,
                                                  const float* __restrict__ W1, const float* __restrict__ b1,
                                                  const float* __restrict__ W2, const float* __restrict__ b2,
                                                  const float* __restrict__ g1, const float* __restrict__ be1,
                                                  const float* __restrict__ g2, const float* __restrict__ be2,
                                                  float* __restrict__ out) {
  __shared__ float hA[D][46];
  __shared__ float den[U];
  __shared__ float Wbuf[FH * D];
  __shared__ float f1s[D][FH + 1];
  __shared__ float f2T[D][46];
  const int b = blockIdx.x;
  const int tid = threadIdx.x;
  const float* hc = hC + (size_t)b * U * (D + 1);
  if (tid < U) den[tid] = 1.0f / hc[tid * (D + 1) + D];
  for (int i = tid; i < FH * D; i += 256) Wbuf[i] = W1[i];
  __syncthreads();
  for (int i = tid; i < U * D; i += 256) {
    const int u = i / D, d = i - u * D;
    hA[u][d] = hc[u * (D + 1) + d] * den[u];
  }
  __syncthreads();
  if (tid < U) {
    const int u = tid;
    float mean = 0.f;
    for (int d = 0; d < D; ++d) mean += hA[u][d];
    mean *= (1.0f / D);
    float var = 0.f;
    for (int d = 0; d < D; ++d) { float t = hA[u][d] - mean; var += t * t; }
    var *= (1.0f / D);
    const float inv = 1.0f / sqrtf(var + LN_EPS);
    for (int d = 0; d < D; ++d) hA[u][d] = g1[d] * ((hA[u][d] - mean) * inv) + be1[d];
  }
  __syncthreads();
  for (int i = tid; i < D * FH; i += 256) {
    const int d = i >> 7, hh = i & 127;
    float acc = b1[hh];
    for (int uu = 0; uu < U; ++uu) acc = fmaf(hA[uu][d], Wbuf[hh * D + uu], acc);
    f1s[d][hh] = fmaxf(acc, 0.f);
  }
  __syncthreads();
  for (int i = tid; i < U * FH; i += 256) Wbuf[i] = W2[i];
  __syncthreads();
  for (int i = tid; i < U * D; i += 256) {
    const int u = i / D, d = i - u * D;
    float acc = b2[u];
    for (int h = 0; h < FH; ++h) acc = fmaf(f1s[d][h], Wbuf[u * FH + h], acc);
    f2T[u][d] = acc;
  }
  __syncthreads();
  if (tid < U) {
    const int u = tid;
    float mean = 0.f;
    for (int d = 0; d < D; ++d) mean += f2T[u][d];
    mean *= (1.0f / D);
    float var = 0.f;
    for (int d = 0; d < D; ++d) { float t = f2T[u][d] - mean; var += t * t; }
    var *= (1.0f / D);
    const float inv = 1.0f / sqrtf(var + LN_EPS);
    float* ob = out + ((size_t)b * U + u) * D;
    for (int d = 0; d < D; ++d) ob[d] = g2[d] * ((f2T[u][d] - mean) * inv) + be2[d];
  }
}

// ---------------------------------------------------------------------------
extern "C" void kernel_launch(void* const* d_in, const int* in_sizes, int n_in,
                              void* d_out, int out_size, void* d_ws, size_t ws_size,
                              hipStream_t stream) {
  const float* x = (const float*)d_in[0];
  const float* W1 = (const float*)d_in[1];
  const float* b1 = (const float*)d_in[2];
  const float* W2 = (const float*)d_in[3];
  const float* b2 = (const float*)d_in[4];
  const float* g1 = (const float*)d_in[5];
  const float* be1 = (const float*)d_in[6];
  const float* g2 = (const float*)d_in[7];
  const float* be2 = (const float*)d_in[8];
  const int* idx = (const int*)d_in[9];
  float* out = (float*)d_out;

  // ws layout: Xh|Xl|Kh|Kl (bf16, 12.6MB) | Ksump | Mpart | Mapx | Cand |
  //            Mcp | Qg | hC   (~15 MiB total)
  // PVpart (NB*NCH*45*46 fp32 = 4.2 MB) overlays Xh|Xl — dead after qkmax.
  const size_t NBF = (size_t)NB * LSEQ * KPAD;  // elems per bf16 buffer
  char* w = (char*)d_ws;
  ushort* Xh = (ushort*)w;
  ushort* Xl = Xh + NBF;
  ushort* Kh = Xl + NBF;
  ushort* Kl = Kh + NBF;
  float* Ksump = (float*)(Kl + NBF);
  float* Mpart = Ksump + (size_t)NB * 16 * KPAD;
  float* Mapx = Mpart + (size_t)SSPLIT * NB * LSEQ;
  int* Cand = (int*)(Mapx + (size_t)NB * LSEQ);
  float* Mcp = (float*)(Cand + NB * TOPC);
  float* Qg = Mcp + (size_t)NB * 16 * TOPC;
  float* hC = Qg + (size_t)NB * U * D;
  float* PVpart = (float*)Xh;  // overlay (stream-ordered: attn_pv after qkmax)

  convert_kernel<<<dim3(16, NB, 2), 256, 0, stream>>>(x, idx, Xh, Xl, Kh, Kl, Ksump);
  qkmax_kernel<<<dim3(LSEQ / 256, NB, SSPLIT), 256, 0, stream>>>(Xh, Xl, Kh, Kl, Mpart);
  meanM_kernel<<<dim3(16, NB), 256, 0, stream>>>(x, Ksump, Mpart, Mapx);
  topk_kernel<<<dim3(NB), 256, 0, stream>>>(Mapx, Cand);
  rescreen_kernel<<<dim3(16, NB), 256, 0, stream>>>(x, idx, Cand, Mcp);
  select_kernel<<<dim3(NB), 256, 0, stream>>>(x, Ksump, Cand, Mcp, Qg);
  attn_pv_kernel<<<dim3(NCH, NB), 256, 0, stream>>>(x, Qg, PVpart);
  combine_kernel<<<dim3(U, NB), 256, 0, stream>>>(PVpart, hC);
  ffn_kernel<<<dim3(NB), 256, 0, stream>>>(hC, W1, b1, W2, b2, g1, be1, g2, be2, out);
}

// Round 11
// 152.821 us; speedup vs baseline: 1.2018x; 1.2018x over previous
//
#include <hip/hip_runtime.h>
#include <hip/hip_bf16.h>

#define D 45
#define LSEQ 4096
#define NB 8
#define U 45
#define FH 128
#define KPAD 48        // padded row length (elems) for bf16 buffers
#define TOPC 64        // screened candidate count (rescreened exactly)
#define SSPLIT 8       // s-range slices for qkmax
#define CH 64          // attn_pv rows per chunk
#define NCH (LSEQ / CH)  // 64 chunks
constexpr float LN_EPS = 1e-12f;

typedef __attribute__((ext_vector_type(8))) short short8v;   // 8 x bf16
typedef __attribute__((ext_vector_type(4))) float float4v;   // MFMA C/D

// ---------------------------------------------------------------------------
// Kernel 1: bf16 conversion (hi part only — screen error budget analysis:
// hh-only dot error rms ~0.01, max ~0.05 over all M values, vs rank-45->64
// gap ~0.4; exact fp32 rescreen of the 64 candidates recovers exactness).
//   z=0: Xh[b][l][0..47] = bf16(x[b][l][d])  (row-major, zero-padded)
//   z=1: Kh[b][s][0..47] = bf16(x[b][idx[s]][d]) + per-chunk Ksum partials
// ---------------------------------------------------------------------------
__global__ __launch_bounds__(256) void convert_kernel(const float* __restrict__ x,
                                                      const int* __restrict__ idx,
                                                      ushort* __restrict__ Xh,
                                                      ushort* __restrict__ Kh,
                                                      float* __restrict__ Ksump) {
  const int c = blockIdx.x, b = blockIdx.y, z = blockIdx.z;
  const int tid = threadIdx.x;
  const int r0 = c * 256;
  const float* xb = x + (size_t)b * LSEQ * D;
  ushort* dh = (z == 0 ? Xh : Kh) + ((size_t)b * LSEQ + r0) * KPAD;
  for (int i = tid; i < 256 * KPAD; i += 256) {
    const int j = i / KPAD, d = i - j * KPAD;
    const int row = (z == 0) ? (r0 + j) : idx[r0 + j];
    const float v = (d < D) ? xb[(size_t)row * D + d] : 0.0f;
    __hip_bfloat16 h = __float2bfloat16(v);
    dh[i] = reinterpret_cast<ushort&>(h);
  }
  if (z == 1) {  // deterministic per-chunk Ksum partial (combined later)
    __shared__ float kp[4][KPAD];
    const int g = tid >> 6, d = tid & 63;
    float acc = 0.f;
    if (d < D)
      for (int j = g; j < 256; j += 4) acc += xb[(size_t)idx[r0 + j] * D + d];
    if (d < KPAD) kp[g][d] = (d < D) ? acc : 0.f;
    __syncthreads();
    if (tid < D)
      Ksump[((size_t)b * 16 + c) * KPAD + tid] =
          kp[0][tid] + kp[1][tid] + kp[2][tid] + kp[3][tid];
  }
}

// ---------------------------------------------------------------------------
// Kernel 2 (HOT): bf16 MFMA QK^T row-max, 16x16x32, 4 l-tiles per wave
// (round-9 structure, hh term only: 2 MFMA per tile per 16-key step).
// C layout (m89-verified): col=lane&15, row=(lane>>4)*4+reg.
// ---------------------------------------------------------------------------
__global__ __launch_bounds__(256) void qkmax_kernel(const ushort* __restrict__ Xh,
                                                    const ushort* __restrict__ Kh,
                                                    float* __restrict__ Mpart) {
  const int b = blockIdx.y, sc = blockIdx.z;
  const int tid = threadIdx.x, lane = tid & 63, wv = tid >> 6;
  const int l0 = blockIdx.x * 256 + wv * 64;  // wave's 64 q-rows
  const int g = lane >> 4, r16 = lane & 15;

  short8v Ah0[4], Ah1[4];
#pragma unroll
  for (int lt = 0; lt < 4; ++lt) {
    const ushort* xh = Xh + ((size_t)b * LSEQ + l0 + lt * 16 + r16) * KPAD + 8 * g;
    Ah0[lt] = *(const short8v*)xh;
    Ah1[lt] = {};
    if (g < 2) Ah1[lt] = *(const short8v*)(xh + 32);
  }

  const ushort* khB = Kh + ((size_t)b * LSEQ + sc * (LSEQ / SSPLIT) + r16) * KPAD + 8 * g;

  float mx[4][4];
#pragma unroll
  for (int lt = 0; lt < 4; ++lt)
#pragma unroll
    for (int r = 0; r < 4; ++r) mx[lt][r] = -INFINITY;

#pragma unroll 2
  for (int st = 0; st < (LSEQ / SSPLIT) / 16; ++st) {
    const ushort* kh = khB + st * (16 * KPAD);
    short8v Bh0 = *(const short8v*)kh;
    short8v Bh1 = {};
    if (g < 2) Bh1 = *(const short8v*)(kh + 32);
#pragma unroll
    for (int lt = 0; lt < 4; ++lt) {
      float4v acc = {0.f, 0.f, 0.f, 0.f};
      acc = __builtin_amdgcn_mfma_f32_16x16x32_bf16(Ah0[lt], Bh0, acc, 0, 0, 0);
      acc = __builtin_amdgcn_mfma_f32_16x16x32_bf16(Ah1[lt], Bh1, acc, 0, 0, 0);
      mx[lt][0] = fmaxf(mx[lt][0], acc[0]);
      mx[lt][1] = fmaxf(mx[lt][1], acc[1]);
      mx[lt][2] = fmaxf(mx[lt][2], acc[2]);
      mx[lt][3] = fmaxf(mx[lt][3], acc[3]);
    }
  }

#pragma unroll
  for (int lt = 0; lt < 4; ++lt)
#pragma unroll
    for (int r = 0; r < 4; ++r) {
      float v = mx[lt][r];
      v = fmaxf(v, __shfl_xor(v, 1));
      v = fmaxf(v, __shfl_xor(v, 2));
      v = fmaxf(v, __shfl_xor(v, 4));
      v = fmaxf(v, __shfl_xor(v, 8));
      if (r16 == 0)
        Mpart[((size_t)sc * NB + b) * LSEQ + l0 + lt * 16 + g * 4 + r] = v;
    }
}

// ---------------------------------------------------------------------------
// Kernel 3: Mapx[b][l] = max_sc(Mpart) - dot(x_l, Ksum)/L   (fp32 mean term)
// ---------------------------------------------------------------------------
__global__ __launch_bounds__(256) void meanM_kernel(const float* __restrict__ x,
                                                    const float* __restrict__ Ksump,
                                                    const float* __restrict__ Mpart,
                                                    float* __restrict__ Mapx) {
  __shared__ float ks[KPAD];
  const int c = blockIdx.x, b = blockIdx.y;
  const int tid = threadIdx.x;
  if (tid < KPAD) {
    float s = 0.f;
    if (tid < D)
      for (int cc = 0; cc < 16; ++cc) s += Ksump[((size_t)b * 16 + cc) * KPAD + tid];
    ks[tid] = s;
  }
  __syncthreads();
  const int l = c * 256 + tid;
  const float* xr = x + ((size_t)b * LSEQ + l) * D;
  float dot = 0.f;
  for (int d = 0; d < D; ++d) dot = fmaf(xr[d], ks[d], dot);
  float mx = Mpart[(size_t)b * LSEQ + l];
  for (int sl = 1; sl < SSPLIT; ++sl)
    mx = fmaxf(mx, Mpart[((size_t)sl * NB + b) * LSEQ + l]);
  Mapx[(size_t)b * LSEQ + l] = mx - dot * (1.0f / LSEQ);
}

// ---------------------------------------------------------------------------
// Kernel 4: radix-select the top-64 candidate SET by approximate M.
// ---------------------------------------------------------------------------
__global__ __launch_bounds__(256) void topk_kernel(const float* __restrict__ Mapx,
                                                   int* __restrict__ Cand) {
  __shared__ int hist[256];
  __shared__ int wsum[4];
  __shared__ int bin_s, need_s, cntG_s, cntEq_s, minv_s;
  __shared__ int eqIdx[LSEQ];
  const int b = blockIdx.x;
  const int tid = threadIdx.x;
  const int lane = tid & 63, wv = tid >> 6;
  uint32_t kreg[16];
#pragma unroll
  for (int k2 = 0; k2 < 16; ++k2) {
    const int l = tid + (k2 << 8);
    uint32_t u = __float_as_uint(Mapx[(size_t)b * LSEQ + l]);
    u ^= (u & 0x80000000u) ? 0xFFFFFFFFu : 0x80000000u;
    kreg[k2] = u;
  }
  const uint32_t pmaskA[4] = {0u, 0xFF000000u, 0xFFFF0000u, 0xFFFFFF00u};
  uint32_t P = 0;
  int need = TOPC;
#pragma unroll
  for (int r = 0; r < 4; ++r) {
    const int shift = 24 - 8 * r;
    hist[tid] = 0;
    __syncthreads();
#pragma unroll
    for (int k2 = 0; k2 < 16; ++k2) {
      const uint32_t key = kreg[k2];
      if (((key ^ P) & pmaskA[r]) == 0) atomicAdd(&hist[(key >> shift) & 0xFF], 1);
    }
    __syncthreads();
    const int h = hist[255 - tid];
    int s = h;
#pragma unroll
    for (int off = 1; off < 64; off <<= 1) {
      int t2 = __shfl_up(s, off);
      if (lane >= off) s += t2;
    }
    if (lane == 63) wsum[wv] = s;
    __syncthreads();
    for (int w2 = 0; w2 < wv; ++w2) s += wsum[w2];
    const int above = s - h;
    if (above < need && s >= need) { bin_s = 255 - tid; need_s = need - above; }
    __syncthreads();
    P |= ((uint32_t)bin_s) << shift;
    need = need_s;
    __syncthreads();
  }
  const uint32_t T = P;

  if (tid == 0) { cntG_s = 0; cntEq_s = 0; }
  __syncthreads();
#pragma unroll
  for (int k2 = 0; k2 < 16; ++k2) {
    const uint32_t key = kreg[k2];
    const int l = tid + (k2 << 8);
    if (key > T) {
      Cand[b * TOPC + atomicAdd(&cntG_s, 1)] = l;
    } else if (key == T) {
      eqIdx[atomicAdd(&cntEq_s, 1)] = l;
    }
  }
  __syncthreads();
  const int G = cntG_s;
  const int nEq = cntEq_s;
  for (int j = 0; j < need; ++j) {
    int mv2 = 0x7FFFFFFF;
    for (int i = tid; i < nEq; i += 256) mv2 = min(mv2, eqIdx[i]);
#pragma unroll
    for (int off = 32; off; off >>= 1) mv2 = min(mv2, __shfl_xor(mv2, off));
    if (lane == 0) wsum[wv] = mv2;
    __syncthreads();
    if (tid == 0) {
      int m2 = min(min(wsum[0], wsum[1]), min(wsum[2], wsum[3]));
      Cand[b * TOPC + G + j] = m2;
      minv_s = m2;
    }
    __syncthreads();
    for (int i = tid; i < nEq; i += 256)
      if (eqIdx[i] == minv_s) eqIdx[i] = 0x7FFFFFFF;
    __syncthreads();
  }
}

// ---------------------------------------------------------------------------
// Kernel 5: exact fp32 rescreen — per 256-key chunk, Mcp[b][c][u] =
// max_s dot(q_cand_u, k_s). K chunk staged in LDS (broadcast reads).
// ---------------------------------------------------------------------------
__global__ __launch_bounds__(256) void rescreen_kernel(const float* __restrict__ x,
                                                       const int* __restrict__ idx,
                                                       const int* __restrict__ Cand,
                                                       float* __restrict__ Mcp) {
  __shared__ float Kr[256][KPAD];
  __shared__ float mred[4][TOPC];
  __shared__ int cl[TOPC];
  const int c = blockIdx.x, b = blockIdx.y;
  const int tid = threadIdx.x;
  const float* xb = x + (size_t)b * LSEQ * D;
  if (tid < TOPC) cl[tid] = Cand[b * TOPC + tid];
  for (int i = tid; i < 256 * D; i += 256) {
    const int j = i / D, d = i - j * D;
    Kr[j][d] = xb[(size_t)idx[c * 256 + j] * D + d];
  }
  __syncthreads();
  const int u = tid & 63, sub = tid >> 6;
  const float* qr = xb + (size_t)cl[u] * D;
  float q[D];
#pragma unroll
  for (int d = 0; d < D; ++d) q[d] = qr[d];
  float mm = -INFINITY;
  for (int s = sub * 64; s < sub * 64 + 64; ++s) {
    float a0 = 0.f, a1 = 0.f;
#pragma unroll
    for (int d = 0; d < 44; d += 4) {
      a0 = fmaf(q[d + 0], Kr[s][d + 0], a0);
      a1 = fmaf(q[d + 1], Kr[s][d + 1], a1);
      a0 = fmaf(q[d + 2], Kr[s][d + 2], a0);
      a1 = fmaf(q[d + 3], Kr[s][d + 3], a1);
    }
    a0 = fmaf(q[44], Kr[s][44], a0);
    mm = fmaxf(mm, a0 + a1);
  }
  mred[sub][u] = mm;
  __syncthreads();
  if (tid < TOPC)
    Mcp[((size_t)b * 16 + c) * TOPC + tid] =
        fmaxf(fmaxf(mred[0][tid], mred[1][tid]), fmaxf(mred[2][tid], mred[3][tid]));
}

// ---------------------------------------------------------------------------
// Kernel 6: exact top-45 among the 64 candidates (value desc, index asc —
// jax.lax.top_k tie order) and gather Qg.
// ---------------------------------------------------------------------------
__global__ __launch_bounds__(256) void select_kernel(const float* __restrict__ x,
                                                     const float* __restrict__ Ksump,
                                                     const int* __restrict__ Cand,
                                                     const float* __restrict__ Mcp,
                                                     float* __restrict__ Qg) {
  __shared__ float ks[KPAD];
  __shared__ unsigned long long keys[TOPC];
  __shared__ int sel[U];
  const int b = blockIdx.x;
  const int tid = threadIdx.x;
  if (tid < KPAD) {
    float s = 0.f;
    if (tid < D)
      for (int cc = 0; cc < 16; ++cc) s += Ksump[((size_t)b * 16 + cc) * KPAD + tid];
    ks[tid] = s;
  }
  __syncthreads();
  if (tid < TOPC) {
    const int l = Cand[b * TOPC + tid];
    float mx = -INFINITY;
    for (int c = 0; c < 16; ++c) mx = fmaxf(mx, Mcp[((size_t)b * 16 + c) * TOPC + tid]);
    const float* xr = x + ((size_t)b * LSEQ + l) * D;
    float dot = 0.f;
    for (int d = 0; d < D; ++d) dot = fmaf(xr[d], ks[d], dot);
    const float Mv = mx - dot * (1.0f / LSEQ);
    uint32_t u = __float_as_uint(Mv);
    u ^= (u & 0x80000000u) ? 0xFFFFFFFFu : 0x80000000u;
    keys[tid] = ((unsigned long long)u << 32) | (unsigned long long)(4095 - l);
  }
  __syncthreads();
  if (tid < TOPC) {
    const unsigned long long ku = keys[tid];
    int rank = 0;
    for (int v = 0; v < TOPC; ++v) rank += (keys[v] > ku);
    if (rank < U) sel[rank] = 4095 - (int)(ku & 0xFFFFFFFFull);
  }
  __syncthreads();
  const float* xb = x + (size_t)b * LSEQ * D;
  for (int i = tid; i < U * D; i += 256) {
    const int u2 = i / D, d = i - u2 * D;
    Qg[(size_t)b * U * D + i] = xb[(size_t)sel[u2] * D + d];
  }
}

// ---------------------------------------------------------------------------
// Kernel 7: sparse attention, 64-row chunks for occupancy.
// ---------------------------------------------------------------------------
__global__ __launch_bounds__(256) void attn_pv_kernel(const float* __restrict__ x,
                                                      const float* __restrict__ Qg,
                                                      float* __restrict__ PVpart) {
  __shared__ float Xs[CH][D + 2];  // [64][47], col 45 = 1.0
  __shared__ float eS[CH][D + 2];
  __shared__ float Qs[U * D];      // 8100 B
  const int chunk = blockIdx.x, b = blockIdx.y;
  const int tid = threadIdx.x;
  const int l0 = chunk * CH;
  const float* xb = x + ((size_t)b * LSEQ + l0) * D;
  for (int i = tid; i < CH * D; i += 256) {
    const int l = i / D, d = i - l * D;
    Xs[l][d] = xb[i];
  }
  const float* qb = Qg + (size_t)b * U * D;
  for (int i = tid; i < U * D; i += 256) Qs[i] = qb[i];
  if (tid < CH) Xs[tid][D] = 1.0f;
  __syncthreads();

  const int l = tid & 63, sub = tid >> 6;
  float xr[D];
#pragma unroll
  for (int d = 0; d < D; ++d) xr[d] = Xs[l][d];
  const float scale = 0.14907119849998599f;  // 1/sqrt(45)
  const int u0 = sub * 12;
  const int uend = (u0 + 12 < U) ? u0 + 12 : U;
  for (int u = u0; u < uend; ++u) {
    float acc = 0.f;
#pragma unroll
    for (int d = 0; d < D; ++d) acc = fmaf(Qs[u * D + d], xr[d], acc);  // uniform LDS bcast
    eS[l][u] = __expf(acc * scale);
  }
  __syncthreads();

  float* outp = PVpart + (size_t)(b * NCH + chunk) * (U * (D + 1));
  for (int idx2 = tid; idx2 < U * (D + 1); idx2 += 256) {
    const int u = idx2 / (D + 1), c = idx2 - u * (D + 1);
    float acc = 0.f;
#pragma unroll 4
    for (int ll = 0; ll < CH; ++ll) acc = fmaf(eS[ll][u], Xs[ll][c], acc);
    outp[idx2] = acc;
  }
}

// ---------------------------------------------------------------------------
// Kernel 8: parallel combine of NCH PV partials -> hC[b][u][0..45]
// ---------------------------------------------------------------------------
__global__ __launch_bounds__(256) void combine_kernel(const float* __restrict__ PVpart,
                                                      float* __restrict__ hC) {
  __shared__ float part[4][D + 1];
  const int u = blockIdx.x, b = blockIdx.y;
  const int tid = threadIdx.x;
  const int g = tid >> 6, col = tid & 63;
  if (col <= D) {
    const float* base = PVpart + ((size_t)b * NCH + g * (NCH / 4)) * (U * (D + 1)) +
                        (size_t)u * (D + 1) + col;
    float s = 0.f;
#pragma unroll 4
    for (int c = 0; c < NCH / 4; ++c) s += base[(size_t)c * (U * (D + 1))];
    part[g][col] = s;
  }
  __syncthreads();
  if (tid <= D)
    hC[((size_t)b * U + u) * (D + 1) + tid] =
        (part[0][tid] + part[1][tid]) + (part[2][tid] + part[3][tid]);
}

// ---------------------------------------------------------------------------
// Kernel 9: normalize -> LN1 -> FFN -> LN2 -> out. Reads only compact hC.
// ---------------------------------------------------------------------------
__global__ __launch_bounds__(256) void ffn_kernel(const float* __restrict__ hC,
                                                  const float* __restrict__ W1, const float* __restrict__ b1,
                                                  const float* __restrict__ W2, const float* __restrict__ b2,
                                                  const float* __restrict__ g1, const float* __restrict__ be1,
                                                  const float* __restrict__ g2, const float* __restrict__ be2,
                                                  float* __restrict__ out) {
  __shared__ float hA[D][46];
  __shared__ float den[U];
  __shared__ float Wbuf[FH * D];
  __shared__ float f1s[D][FH + 1];
  __shared__ float f2T[D][46];
  const int b = blockIdx.x;
  const int tid = threadIdx.x;
  const float* hc = hC + (size_t)b * U * (D + 1);
  if (tid < U) den[tid] = 1.0f / hc[tid * (D + 1) + D];
  for (int i = tid; i < FH * D; i += 256) Wbuf[i] = W1[i];
  __syncthreads();
  for (int i = tid; i < U * D; i += 256) {
    const int u = i / D, d = i - u * D;
    hA[u][d] = hc[u * (D + 1) + d] * den[u];
  }
  __syncthreads();
  if (tid < U) {
    const int u = tid;
    float mean = 0.f;
    for (int d = 0; d < D; ++d) mean += hA[u][d];
    mean *= (1.0f / D);
    float var = 0.f;
    for (int d = 0; d < D; ++d) { float t = hA[u][d] - mean; var += t * t; }
    var *= (1.0f / D);
    const float inv = 1.0f / sqrtf(var + LN_EPS);
    for (int d = 0; d < D; ++d) hA[u][d] = g1[d] * ((hA[u][d] - mean) * inv) + be1[d];
  }
  __syncthreads();
  for (int i = tid; i < D * FH; i += 256) {
    const int d = i >> 7, hh = i & 127;
    float acc = b1[hh];
    for (int uu = 0; uu < U; ++uu) acc = fmaf(hA[uu][d], Wbuf[hh * D + uu], acc);
    f1s[d][hh] = fmaxf(acc, 0.f);
  }
  __syncthreads();
  for (int i = tid; i < U * FH; i += 256) Wbuf[i] = W2[i];
  __syncthreads();
  for (int i = tid; i < U * D; i += 256) {
    const int u = i / D, d = i - u * D;
    float acc = b2[u];
    for (int h = 0; h < FH; ++h) acc = fmaf(f1s[d][h], Wbuf[u * FH + h], acc);
    f2T[u][d] = acc;
  }
  __syncthreads();
  if (tid < U) {
    const int u = tid;
    float mean = 0.f;
    for (int d = 0; d < D; ++d) mean += f2T[u][d];
    mean *= (1.0f / D);
    float var = 0.f;
    for (int d = 0; d < D; ++d) { float t = f2T[u][d] - mean; var += t * t; }
    var *= (1.0f / D);
    const float inv = 1.0f / sqrtf(var + LN_EPS);
    float* ob = out + ((size_t)b * U + u) * D;
    for (int d = 0; d < D; ++d) ob[d] = g2[d] * ((f2T[u][d] - mean) * inv) + be2[d];
  }
}

// ---------------------------------------------------------------------------
extern "C" void kernel_launch(void* const* d_in, const int* in_sizes, int n_in,
                              void* d_out, int out_size, void* d_ws, size_t ws_size,
                              hipStream_t stream) {
  const float* x = (const float*)d_in[0];
  const float* W1 = (const float*)d_in[1];
  const float* b1 = (const float*)d_in[2];
  const float* W2 = (const float*)d_in[3];
  const float* b2 = (const float*)d_in[4];
  const float* g1 = (const float*)d_in[5];
  const float* be1 = (const float*)d_in[6];
  const float* g2 = (const float*)d_in[7];
  const float* be2 = (const float*)d_in[8];
  const int* idx = (const int*)d_in[9];
  float* out = (float*)d_out;

  // ws layout: Xh|Kh (bf16, 6.3MB) | Ksump | Mpart | Mapx | Cand | Mcp | Qg |
  //            hC   (~9 MiB total)
  // PVpart (NB*NCH*45*46 fp32 = 4.2 MB) overlays Xh|Kh — both dead after qkmax.
  const size_t NBF = (size_t)NB * LSEQ * KPAD;  // elems per bf16 buffer
  char* w = (char*)d_ws;
  ushort* Xh = (ushort*)w;
  ushort* Kh = Xh + NBF;
  float* Ksump = (float*)(Kh + NBF);
  float* Mpart = Ksump + (size_t)NB * 16 * KPAD;
  float* Mapx = Mpart + (size_t)SSPLIT * NB * LSEQ;
  int* Cand = (int*)(Mapx + (size_t)NB * LSEQ);
  float* Mcp = (float*)(Cand + NB * TOPC);
  float* Qg = Mcp + (size_t)NB * 16 * TOPC;
  float* hC = Qg + (size_t)NB * U * D;
  float* PVpart = (float*)Xh;  // overlay (stream-ordered: attn_pv after qkmax)

  convert_kernel<<<dim3(16, NB, 2), 256, 0, stream>>>(x, idx, Xh, Kh, Ksump);
  qkmax_kernel<<<dim3(LSEQ / 256, NB, SSPLIT), 256, 0, stream>>>(Xh, Kh, Mpart);
  meanM_kernel<<<dim3(16, NB), 256, 0, stream>>>(x, Ksump, Mpart, Mapx);
  topk_kernel<<<dim3(NB), 256, 0, stream>>>(Mapx, Cand);
  rescreen_kernel<<<dim3(16, NB), 256, 0, stream>>>(x, idx, Cand, Mcp);
  select_kernel<<<dim3(NB), 256, 0, stream>>>(x, Ksump, Cand, Mcp, Qg);
  attn_pv_kernel<<<dim3(NCH, NB), 256, 0, stream>>>(x, Qg, PVpart);
  combine_kernel<<<dim3(U, NB), 256, 0, stream>>>(PVpart, hC);
  ffn_kernel<<<dim3(NB), 256, 0, stream>>>(hC, W1, b1, W2, b2, g1, be1, g2, be2, out);
}

// Round 12
// 132.366 us; speedup vs baseline: 1.3875x; 1.1545x over previous
//
#include <hip/hip_runtime.h>
#include <hip/hip_bf16.h>

#define D 45
#define LSEQ 4096
#define NB 8
#define U 45
#define FH 128
#define KPAD 48        // padded row length (elems) for bf16 buffers
#define TOPC 64        // screened candidate count (rescreened exactly)
#define SSPLIT 8       // s-range slices for qkmax
#define CH 64          // attn_pv rows per chunk
#define NCH (LSEQ / CH)  // 64 chunks
constexpr float LN_EPS = 1e-12f;

typedef __attribute__((ext_vector_type(8))) short short8v;           // 8 x bf16
typedef __attribute__((ext_vector_type(4))) float float4v;           // MFMA C/D
typedef __attribute__((ext_vector_type(4))) unsigned short ushort4v; // 4 x bf16 store

__device__ inline ushort f2bf(float v) {
  __hip_bfloat16 h = __float2bfloat16(v);
  return reinterpret_cast<ushort&>(h);
}

// ---------------------------------------------------------------------------
// Kernel 1: bf16 conversion (hi part only; screen rescreened exactly later).
// 4-elem groups (KPAD divisible by 4): per thread 12 unrolled groups, each
// 4 coalesced fp32 loads -> packed 8B ushort4 store. Forces ILP (round-11's
// VGPR=8 serial-chain pathology: 44.8 us for 13 MB).
//   z=0: Xh[b][l][0..47] = bf16(x[b][l][d]);  z=1: Kh gathered + Ksum partials
// ---------------------------------------------------------------------------
__global__ __launch_bounds__(256) void convert_kernel(const float* __restrict__ x,
                                                      const int* __restrict__ idx,
                                                      ushort* __restrict__ Xh,
                                                      ushort* __restrict__ Kh,
                                                      float* __restrict__ Ksump) {
  const int c = blockIdx.x, b = blockIdx.y, z = blockIdx.z;
  const int tid = threadIdx.x;
  const int r0 = c * 256;
  const float* xb = x + (size_t)b * LSEQ * D;
  ushort* dh = (z == 0 ? Xh : Kh) + ((size_t)b * LSEQ + r0) * KPAD;
#pragma unroll
  for (int it = 0; it < 12; ++it) {
    const int gi = tid + it * 256;  // 4-elem group index within 256 rows
    const int row = gi / 12;
    const int d0 = (gi - row * 12) * 4;
    const int srow = (z == 0) ? (r0 + row) : idx[r0 + row];
    const float* src = xb + (size_t)srow * D + d0;
    float v0 = src[0], v1 = 0.f, v2 = 0.f, v3 = 0.f;
    if (d0 < 44) { v1 = src[1]; v2 = src[2]; v3 = src[3]; }
    ushort4v o = {f2bf(v0), f2bf(v1), f2bf(v2), f2bf(v3)};
    *reinterpret_cast<ushort4v*>(dh + gi * 4) = o;
  }
  if (z == 1) {  // deterministic per-chunk Ksum partial (4 indep chains/thread)
    __shared__ float kp[4][KPAD];
    const int g = tid >> 6, d = tid & 63;
    if (d < D) {
      float a0 = 0.f, a1 = 0.f, a2 = 0.f, a3 = 0.f;
      const int j0 = g * 64;
      for (int j = j0; j < j0 + 64; j += 4) {
        a0 += xb[(size_t)idx[r0 + j + 0] * D + d];
        a1 += xb[(size_t)idx[r0 + j + 1] * D + d];
        a2 += xb[(size_t)idx[r0 + j + 2] * D + d];
        a3 += xb[(size_t)idx[r0 + j + 3] * D + d];
      }
      kp[g][d] = (a0 + a1) + (a2 + a3);
    } else if (d < KPAD) {
      kp[g][d] = 0.f;
    }
    __syncthreads();
    if (tid < D)
      Ksump[((size_t)b * 16 + c) * KPAD + tid] =
          kp[0][tid] + kp[1][tid] + kp[2][tid] + kp[3][tid];
  }
}

// ---------------------------------------------------------------------------
// Kernel 2 (HOT): bf16 MFMA QK^T row-max, 16x16x32, 4 l-tiles per wave
// (hh term only). C layout (m89): col=lane&15, row=(lane>>4)*4+reg.
// ---------------------------------------------------------------------------
__global__ __launch_bounds__(256) void qkmax_kernel(const ushort* __restrict__ Xh,
                                                    const ushort* __restrict__ Kh,
                                                    float* __restrict__ Mpart) {
  const int b = blockIdx.y, sc = blockIdx.z;
  const int tid = threadIdx.x, lane = tid & 63, wv = tid >> 6;
  const int l0 = blockIdx.x * 256 + wv * 64;  // wave's 64 q-rows
  const int g = lane >> 4, r16 = lane & 15;

  short8v Ah0[4], Ah1[4];
#pragma unroll
  for (int lt = 0; lt < 4; ++lt) {
    const ushort* xh = Xh + ((size_t)b * LSEQ + l0 + lt * 16 + r16) * KPAD + 8 * g;
    Ah0[lt] = *(const short8v*)xh;
    Ah1[lt] = {};
    if (g < 2) Ah1[lt] = *(const short8v*)(xh + 32);
  }

  const ushort* khB = Kh + ((size_t)b * LSEQ + sc * (LSEQ / SSPLIT) + r16) * KPAD + 8 * g;

  float mx[4][4];
#pragma unroll
  for (int lt = 0; lt < 4; ++lt)
#pragma unroll
    for (int r = 0; r < 4; ++r) mx[lt][r] = -INFINITY;

#pragma unroll 2
  for (int st = 0; st < (LSEQ / SSPLIT) / 16; ++st) {
    const ushort* kh = khB + st * (16 * KPAD);
    short8v Bh0 = *(const short8v*)kh;
    short8v Bh1 = {};
    if (g < 2) Bh1 = *(const short8v*)(kh + 32);
#pragma unroll
    for (int lt = 0; lt < 4; ++lt) {
      float4v acc = {0.f, 0.f, 0.f, 0.f};
      acc = __builtin_amdgcn_mfma_f32_16x16x32_bf16(Ah0[lt], Bh0, acc, 0, 0, 0);
      acc = __builtin_amdgcn_mfma_f32_16x16x32_bf16(Ah1[lt], Bh1, acc, 0, 0, 0);
      mx[lt][0] = fmaxf(mx[lt][0], acc[0]);
      mx[lt][1] = fmaxf(mx[lt][1], acc[1]);
      mx[lt][2] = fmaxf(mx[lt][2], acc[2]);
      mx[lt][3] = fmaxf(mx[lt][3], acc[3]);
    }
  }

#pragma unroll
  for (int lt = 0; lt < 4; ++lt)
#pragma unroll
    for (int r = 0; r < 4; ++r) {
      float v = mx[lt][r];
      v = fmaxf(v, __shfl_xor(v, 1));
      v = fmaxf(v, __shfl_xor(v, 2));
      v = fmaxf(v, __shfl_xor(v, 4));
      v = fmaxf(v, __shfl_xor(v, 8));
      if (r16 == 0)
        Mpart[((size_t)sc * NB + b) * LSEQ + l0 + lt * 16 + g * 4 + r] = v;
    }
}

// ---------------------------------------------------------------------------
// Kernel 3: Mapx[b][l] = max_sc(Mpart) - dot(x_l, Ksum)/L   (fp32 mean term)
// ---------------------------------------------------------------------------
__global__ __launch_bounds__(256) void meanM_kernel(const float* __restrict__ x,
                                                    const float* __restrict__ Ksump,
                                                    const float* __restrict__ Mpart,
                                                    float* __restrict__ Mapx) {
  __shared__ float ks[KPAD];
  const int c = blockIdx.x, b = blockIdx.y;
  const int tid = threadIdx.x;
  if (tid < KPAD) {
    float s = 0.f;
    if (tid < D)
      for (int cc = 0; cc < 16; ++cc) s += Ksump[((size_t)b * 16 + cc) * KPAD + tid];
    ks[tid] = s;
  }
  __syncthreads();
  const int l = c * 256 + tid;
  const float* xr = x + ((size_t)b * LSEQ + l) * D;
  float dot = 0.f;
  for (int d = 0; d < D; ++d) dot = fmaf(xr[d], ks[d], dot);
  float mx = Mpart[(size_t)b * LSEQ + l];
  for (int sl = 1; sl < SSPLIT; ++sl)
    mx = fmaxf(mx, Mpart[((size_t)sl * NB + b) * LSEQ + l]);
  Mapx[(size_t)b * LSEQ + l] = mx - dot * (1.0f / LSEQ);
}

// ---------------------------------------------------------------------------
// Kernel 4: radix-select the top-64 candidate SET by approximate M.
// ---------------------------------------------------------------------------
__global__ __launch_bounds__(256) void topk_kernel(const float* __restrict__ Mapx,
                                                   int* __restrict__ Cand) {
  __shared__ int hist[256];
  __shared__ int wsum[4];
  __shared__ int bin_s, need_s, cntG_s, cntEq_s, minv_s;
  __shared__ int eqIdx[LSEQ];
  const int b = blockIdx.x;
  const int tid = threadIdx.x;
  const int lane = tid & 63, wv = tid >> 6;
  uint32_t kreg[16];
#pragma unroll
  for (int k2 = 0; k2 < 16; ++k2) {
    const int l = tid + (k2 << 8);
    uint32_t u = __float_as_uint(Mapx[(size_t)b * LSEQ + l]);
    u ^= (u & 0x80000000u) ? 0xFFFFFFFFu : 0x80000000u;
    kreg[k2] = u;
  }
  const uint32_t pmaskA[4] = {0u, 0xFF000000u, 0xFFFF0000u, 0xFFFFFF00u};
  uint32_t P = 0;
  int need = TOPC;
#pragma unroll
  for (int r = 0; r < 4; ++r) {
    const int shift = 24 - 8 * r;
    hist[tid] = 0;
    __syncthreads();
#pragma unroll
    for (int k2 = 0; k2 < 16; ++k2) {
      const uint32_t key = kreg[k2];
      if (((key ^ P) & pmaskA[r]) == 0) atomicAdd(&hist[(key >> shift) & 0xFF], 1);
    }
    __syncthreads();
    const int h = hist[255 - tid];
    int s = h;
#pragma unroll
    for (int off = 1; off < 64; off <<= 1) {
      int t2 = __shfl_up(s, off);
      if (lane >= off) s += t2;
    }
    if (lane == 63) wsum[wv] = s;
    __syncthreads();
    for (int w2 = 0; w2 < wv; ++w2) s += wsum[w2];
    const int above = s - h;
    if (above < need && s >= need) { bin_s = 255 - tid; need_s = need - above; }
    __syncthreads();
    P |= ((uint32_t)bin_s) << shift;
    need = need_s;
    __syncthreads();
  }
  const uint32_t T = P;

  if (tid == 0) { cntG_s = 0; cntEq_s = 0; }
  __syncthreads();
#pragma unroll
  for (int k2 = 0; k2 < 16; ++k2) {
    const uint32_t key = kreg[k2];
    const int l = tid + (k2 << 8);
    if (key > T) {
      Cand[b * TOPC + atomicAdd(&cntG_s, 1)] = l;
    } else if (key == T) {
      eqIdx[atomicAdd(&cntEq_s, 1)] = l;
    }
  }
  __syncthreads();
  const int G = cntG_s;
  const int nEq = cntEq_s;
  for (int j = 0; j < need; ++j) {
    int mv2 = 0x7FFFFFFF;
    for (int i = tid; i < nEq; i += 256) mv2 = min(mv2, eqIdx[i]);
#pragma unroll
    for (int off = 32; off; off >>= 1) mv2 = min(mv2, __shfl_xor(mv2, off));
    if (lane == 0) wsum[wv] = mv2;
    __syncthreads();
    if (tid == 0) {
      int m2 = min(min(wsum[0], wsum[1]), min(wsum[2], wsum[3]));
      Cand[b * TOPC + G + j] = m2;
      minv_s = m2;
    }
    __syncthreads();
    for (int i = tid; i < nEq; i += 256)
      if (eqIdx[i] == minv_s) eqIdx[i] = 0x7FFFFFFF;
    __syncthreads();
  }
}

// ---------------------------------------------------------------------------
// Kernel 5: exact fp32 rescreen — per 256-key chunk, Mcp[b][c][u] =
// max_s dot(q_cand_u, k_s). K chunk staged in LDS (broadcast reads).
// ---------------------------------------------------------------------------
__global__ __launch_bounds__(256) void rescreen_kernel(const float* __restrict__ x,
                                                       const int* __restrict__ idx,
                                                       const int* __restrict__ Cand,
                                                       float* __restrict__ Mcp) {
  __shared__ float Kr[256][KPAD];
  __shared__ float mred[4][TOPC];
  __shared__ int cl[TOPC];
  const int c = blockIdx.x, b = blockIdx.y;
  const int tid = threadIdx.x;
  const float* xb = x + (size_t)b * LSEQ * D;
  if (tid < TOPC) cl[tid] = Cand[b * TOPC + tid];
  for (int i = tid; i < 256 * D; i += 256) {
    const int j = i / D, d = i - j * D;
    Kr[j][d] = xb[(size_t)idx[c * 256 + j] * D + d];
  }
  __syncthreads();
  const int u = tid & 63, sub = tid >> 6;
  const float* qr = xb + (size_t)cl[u] * D;
  float q[D];
#pragma unroll
  for (int d = 0; d < D; ++d) q[d] = qr[d];
  float mm = -INFINITY;
  for (int s = sub * 64; s < sub * 64 + 64; ++s) {
    float a0 = 0.f, a1 = 0.f;
#pragma unroll
    for (int d = 0; d < 44; d += 4) {
      a0 = fmaf(q[d + 0], Kr[s][d + 0], a0);
      a1 = fmaf(q[d + 1], Kr[s][d + 1], a1);
      a0 = fmaf(q[d + 2], Kr[s][d + 2], a0);
      a1 = fmaf(q[d + 3], Kr[s][d + 3], a1);
    }
    a0 = fmaf(q[44], Kr[s][44], a0);
    mm = fmaxf(mm, a0 + a1);
  }
  mred[sub][u] = mm;
  __syncthreads();
  if (tid < TOPC)
    Mcp[((size_t)b * 16 + c) * TOPC + tid] =
        fmaxf(fmaxf(mred[0][tid], mred[1][tid]), fmaxf(mred[2][tid], mred[3][tid]));
}

// ---------------------------------------------------------------------------
// Kernel 6: exact top-45 among the 64 candidates (value desc, index asc —
// jax.lax.top_k tie order) and gather Qg.
// ---------------------------------------------------------------------------
__global__ __launch_bounds__(256) void select_kernel(const float* __restrict__ x,
                                                     const float* __restrict__ Ksump,
                                                     const int* __restrict__ Cand,
                                                     const float* __restrict__ Mcp,
                                                     float* __restrict__ Qg) {
  __shared__ float ks[KPAD];
  __shared__ unsigned long long keys[TOPC];
  __shared__ int sel[U];
  const int b = blockIdx.x;
  const int tid = threadIdx.x;
  if (tid < KPAD) {
    float s = 0.f;
    if (tid < D)
      for (int cc = 0; cc < 16; ++cc) s += Ksump[((size_t)b * 16 + cc) * KPAD + tid];
    ks[tid] = s;
  }
  __syncthreads();
  if (tid < TOPC) {
    const int l = Cand[b * TOPC + tid];
    float mx = -INFINITY;
    for (int c = 0; c < 16; ++c) mx = fmaxf(mx, Mcp[((size_t)b * 16 + c) * TOPC + tid]);
    const float* xr = x + ((size_t)b * LSEQ + l) * D;
    float dot = 0.f;
    for (int d = 0; d < D; ++d) dot = fmaf(xr[d], ks[d], dot);
    const float Mv = mx - dot * (1.0f / LSEQ);
    uint32_t u = __float_as_uint(Mv);
    u ^= (u & 0x80000000u) ? 0xFFFFFFFFu : 0x80000000u;
    keys[tid] = ((unsigned long long)u << 32) | (unsigned long long)(4095 - l);
  }
  __syncthreads();
  if (tid < TOPC) {
    const unsigned long long ku = keys[tid];
    int rank = 0;
    for (int v = 0; v < TOPC; ++v) rank += (keys[v] > ku);
    if (rank < U) sel[rank] = 4095 - (int)(ku & 0xFFFFFFFFull);
  }
  __syncthreads();
  const float* xb = x + (size_t)b * LSEQ * D;
  for (int i = tid; i < U * D; i += 256) {
    const int u2 = i / D, d = i - u2 * D;
    Qg[(size_t)b * U * D + i] = xb[(size_t)sel[u2] * D + d];
  }
}

// ---------------------------------------------------------------------------
// Kernel 7: sparse attention, 64-row chunks for occupancy.
// ---------------------------------------------------------------------------
__global__ __launch_bounds__(256) void attn_pv_kernel(const float* __restrict__ x,
                                                      const float* __restrict__ Qg,
                                                      float* __restrict__ PVpart) {
  __shared__ float Xs[CH][D + 2];  // [64][47], col 45 = 1.0
  __shared__ float eS[CH][D + 2];
  __shared__ float Qs[U * D];      // 8100 B
  const int chunk = blockIdx.x, b = blockIdx.y;
  const int tid = threadIdx.x;
  const int l0 = chunk * CH;
  const float* xb = x + ((size_t)b * LSEQ + l0) * D;
  for (int i = tid; i < CH * D; i += 256) {
    const int l = i / D, d = i - l * D;
    Xs[l][d] = xb[i];
  }
  const float* qb = Qg + (size_t)b * U * D;
  for (int i = tid; i < U * D; i += 256) Qs[i] = qb[i];
  if (tid < CH) Xs[tid][D] = 1.0f;
  __syncthreads();

  const int l = tid & 63, sub = tid >> 6;
  float xr[D];
#pragma unroll
  for (int d = 0; d < D; ++d) xr[d] = Xs[l][d];
  const float scale = 0.14907119849998599f;  // 1/sqrt(45)
  const int u0 = sub * 12;
  const int uend = (u0 + 12 < U) ? u0 + 12 : U;
  for (int u = u0; u < uend; ++u) {
    float acc = 0.f;
#pragma unroll
    for (int d = 0; d < D; ++d) acc = fmaf(Qs[u * D + d], xr[d], acc);  // uniform LDS bcast
    eS[l][u] = __expf(acc * scale);
  }
  __syncthreads();

  float* outp = PVpart + (size_t)(b * NCH + chunk) * (U * (D + 1));
  for (int idx2 = tid; idx2 < U * (D + 1); idx2 += 256) {
    const int u = idx2 / (D + 1), c = idx2 - u * (D + 1);
    float acc = 0.f;
#pragma unroll 4
    for (int ll = 0; ll < CH; ++ll) acc = fmaf(eS[ll][u], Xs[ll][c], acc);
    outp[idx2] = acc;
  }
}

// ---------------------------------------------------------------------------
// Kernel 8: parallel combine of NCH PV partials -> hC[b][u][0..45]
// ---------------------------------------------------------------------------
__global__ __launch_bounds__(256) void combine_kernel(const float* __restrict__ PVpart,
                                                      float* __restrict__ hC) {
  __shared__ float part[4][D + 1];
  const int u = blockIdx.x, b = blockIdx.y;
  const int tid = threadIdx.x;
  const int g = tid >> 6, col = tid & 63;
  if (col <= D) {
    const float* base = PVpart + ((size_t)b * NCH + g * (NCH / 4)) * (U * (D + 1)) +
                        (size_t)u * (D + 1) + col;
    float s = 0.f;
#pragma unroll 4
    for (int c = 0; c < NCH / 4; ++c) s += base[(size_t)c * (U * (D + 1))];
    part[g][col] = s;
  }
  __syncthreads();
  if (tid <= D)
    hC[((size_t)b * U + u) * (D + 1) + tid] =
        (part[0][tid] + part[1][tid]) + (part[2][tid] + part[3][tid]);
}

// ---------------------------------------------------------------------------
// Kernel 9: normalize -> LN1 -> FFN -> LN2 -> out. Reads only compact hC.
// ---------------------------------------------------------------------------
__global__ __launch_bounds__(256) void ffn_kernel(const float* __restrict__ hC,
                                                  const float* __restrict__ W1, const float* __restrict__ b1,
                                                  const float* __restrict__ W2, const float* __restrict__ b2,
                                                  const float* __restrict__ g1, const float* __restrict__ be1,
                                                  const float* __restrict__ g2, const float* __restrict__ be2,
                                                  float* __restrict__ out) {
  __shared__ float hA[D][46];
  __shared__ float den[U];
  __shared__ float Wbuf[FH * D];
  __shared__ float f1s[D][FH + 1];
  __shared__ float f2T[D][46];
  const int b = blockIdx.x;
  const int tid = threadIdx.x;
  const float* hc = hC + (size_t)b * U * (D + 1);
  if (tid < U) den[tid] = 1.0f / hc[tid * (D + 1) + D];
  for (int i = tid; i < FH * D; i += 256) Wbuf[i] = W1[i];
  __syncthreads();
  for (int i = tid; i < U * D; i += 256) {
    const int u = i / D, d = i - u * D;
    hA[u][d] = hc[u * (D + 1) + d] * den[u];
  }
  __syncthreads();
  if (tid < U) {
    const int u = tid;
    float mean = 0.f;
    for (int d = 0; d < D; ++d) mean += hA[u][d];
    mean *= (1.0f / D);
    float var = 0.f;
    for (int d = 0; d < D; ++d) { float t = hA[u][d] - mean; var += t * t; }
    var *= (1.0f / D);
    const float inv = 1.0f / sqrtf(var + LN_EPS);
    for (int d = 0; d < D; ++d) hA[u][d] = g1[d] * ((hA[u][d] - mean) * inv) + be1[d];
  }
  __syncthreads();
  for (int i = tid; i < D * FH; i += 256) {
    const int d = i >> 7, hh = i & 127;
    float acc = b1[hh];
    for (int uu = 0; uu < U; ++uu) acc = fmaf(hA[uu][d], Wbuf[hh * D + uu], acc);
    f1s[d][hh] = fmaxf(acc, 0.f);
  }
  __syncthreads();
  for (int i = tid; i < U * FH; i += 256) Wbuf[i] = W2[i];
  __syncthreads();
  for (int i = tid; i < U * D; i += 256) {
    const int u = i / D, d = i - u * D;
    float acc = b2[u];
    for (int h = 0; h < FH; ++h) acc = fmaf(f1s[d][h], Wbuf[u * FH + h], acc);
    f2T[u][d] = acc;
  }
  __syncthreads();
  if (tid < U) {
    const int u = tid;
    float mean = 0.f;
    for (int d = 0; d < D; ++d) mean += f2T[u][d];
    mean *= (1.0f / D);
    float var = 0.f;
    for (int d = 0; d < D; ++d) { float t = f2T[u][d] - mean; var += t * t; }
    var *= (1.0f / D);
    const float inv = 1.0f / sqrtf(var + LN_EPS);
    float* ob = out + ((size_t)b * U + u) * D;
    for (int d = 0; d < D; ++d) ob[d] = g2[d] * ((f2T[u][d] - mean) * inv) + be2[d];
  }
}

// ---------------------------------------------------------------------------
extern "C" void kernel_launch(void* const* d_in, const int* in_sizes, int n_in,
                              void* d_out, int out_size, void* d_ws, size_t ws_size,
                              hipStream_t stream) {
  const float* x = (const float*)d_in[0];
  const float* W1 = (const float*)d_in[1];
  const float* b1 = (const float*)d_in[2];
  const float* W2 = (const float*)d_in[3];
  const float* b2 = (const float*)d_in[4];
  const float* g1 = (const float*)d_in[5];
  const float* be1 = (const float*)d_in[6];
  const float* g2 = (const float*)d_in[7];
  const float* be2 = (const float*)d_in[8];
  const int* idx = (const int*)d_in[9];
  float* out = (float*)d_out;

  // ws layout: Xh|Kh (bf16, 6.3MB) | Ksump | Mpart | Mapx | Cand | Mcp | Qg |
  //            hC   (~9 MiB total)
  // PVpart (NB*NCH*45*46 fp32 = 4.2 MB) overlays Xh|Kh — both dead after qkmax.
  const size_t NBF = (size_t)NB * LSEQ * KPAD;  // elems per bf16 buffer
  char* w = (char*)d_ws;
  ushort* Xh = (ushort*)w;
  ushort* Kh = Xh + NBF;
  float* Ksump = (float*)(Kh + NBF);
  float* Mpart = Ksump + (size_t)NB * 16 * KPAD;
  float* Mapx = Mpart + (size_t)SSPLIT * NB * LSEQ;
  int* Cand = (int*)(Mapx + (size_t)NB * LSEQ);
  float* Mcp = (float*)(Cand + NB * TOPC);
  float* Qg = Mcp + (size_t)NB * 16 * TOPC;
  float* hC = Qg + (size_t)NB * U * D;
  float* PVpart = (float*)Xh;  // overlay (stream-ordered: attn_pv after qkmax)

  convert_kernel<<<dim3(16, NB, 2), 256, 0, stream>>>(x, idx, Xh, Kh, Ksump);
  qkmax_kernel<<<dim3(LSEQ / 256, NB, SSPLIT), 256, 0, stream>>>(Xh, Kh, Mpart);
  meanM_kernel<<<dim3(16, NB), 256, 0, stream>>>(x, Ksump, Mpart, Mapx);
  topk_kernel<<<dim3(NB), 256, 0, stream>>>(Mapx, Cand);
  rescreen_kernel<<<dim3(16, NB), 256, 0, stream>>>(x, idx, Cand, Mcp);
  select_kernel<<<dim3(NB), 256, 0, stream>>>(x, Ksump, Cand, Mcp, Qg);
  attn_pv_kernel<<<dim3(NCH, NB), 256, 0, stream>>>(x, Qg, PVpart);
  combine_kernel<<<dim3(U, NB), 256, 0, stream>>>(PVpart, hC);
  ffn_kernel<<<dim3(NB), 256, 0, stream>>>(hC, W1, b1, W2, b2, g1, be1, g2, be2, out);
}